// Round 1
// 419.512 us; speedup vs baseline: 1.0063x; 1.0063x over previous
//
#include <hip/hip_runtime.h>

// Problem constants (from reference setup_inputs): B=4, D=2048, L=8192, K=3, pad=1
constexpr int B = 4;
constexpr int D = 2048;
constexpr int L = 8192;
constexpr int KW = 3;
constexpr int PAD = 1;
constexpr int L_OUT = L + 2 * PAD - KW + 1;  // 8192
constexpr int L4 = L / 4;                    // 2048 float4 per row

__global__ __launch_bounds__(256) void dwconv1d_k3(
    const float* __restrict__ in,    // [B, D, L]
    const float* __restrict__ w,     // [D, 3]
    const float* __restrict__ bias,  // [D]
    float* __restrict__ out)         // [B, D, L_OUT]
{
    const int gid  = blockIdx.x * 256 + threadIdx.x;
    const int row  = gid >> 11;       // gid / L4   (L4 = 2048)
    const int l4   = gid & (L4 - 1);  // gid % L4
    const int l    = l4 << 2;
    const int lane = threadIdx.x & 63;

    const float* __restrict__ rowp = in + (size_t)row * L;

    // Main aligned vector load: wave reads 1024B contiguous (optimal line usage)
    const float4 c = *(const float4*)(rowp + l);

    // Halo exchange in-register: every wave holds 64 consecutive float4 of ONE
    // row (row spans 2048 l4, 64-aligned), so lane i-1 owns in[l-1] (=its c.w)
    // and lane i+1 owns in[l+4] (=its c.x). Replaces two 16-line strided scalar
    // loads per wave with two shuffles + a 2-lane predicated edge load.
    float left  = __shfl_up(c.w, 1);
    float right = __shfl_down(c.x, 1);
    if (lane == 0)  left  = (l > 0)     ? rowp[l - 1] : 0.0f;  // zero-pad at l=0
    if (lane == 63) right = (l + 4 < L) ? rowp[l + 4] : 0.0f;  // zero-pad at end

    // Per-channel weights: d is uniform across the block (block = 1024 floats of
    // one row). readfirstlane moves it to SGPR so the compiler emits scalar
    // (SMEM) loads instead of 4 broadcast VMEM loads per wave.
    const int d  = row & (D - 1);     // row % D
    const int du = __builtin_amdgcn_readfirstlane(d);
    const float w0 = w[du * KW + 0];
    const float w1 = w[du * KW + 1];
    const float w2 = w[du * KW + 2];
    const float bv = bias[du];

    // out[l+j] = bias + in[l+j-1]*w0 + in[l+j]*w1 + in[l+j+1]*w2
    // Accumulation order matches reference: bias, then k=0,1,2.
    float4 o;
    o.x = bv; o.x = fmaf(left, w0, o.x); o.x = fmaf(c.x, w1, o.x); o.x = fmaf(c.y,  w2, o.x);
    o.y = bv; o.y = fmaf(c.x,  w0, o.y); o.y = fmaf(c.y, w1, o.y); o.y = fmaf(c.z,  w2, o.y);
    o.z = bv; o.z = fmaf(c.y,  w0, o.z); o.z = fmaf(c.z, w1, o.z); o.z = fmaf(c.w,  w2, o.z);
    o.w = bv; o.w = fmaf(c.z,  w0, o.w); o.w = fmaf(c.w, w1, o.w); o.w = fmaf(right, w2, o.w);

    *(float4*)(out + (size_t)row * L_OUT + l) = o;
}

extern "C" void kernel_launch(void* const* d_in, const int* in_sizes, int n_in,
                              void* d_out, int out_size, void* d_ws, size_t ws_size,
                              hipStream_t stream) {
    const float* in   = (const float*)d_in[0];
    const float* w    = (const float*)d_in[1];
    const float* bias = (const float*)d_in[2];
    // d_in[3] is padding (int scalar) — fixed at 1 for this problem.
    float* out = (float*)d_out;

    constexpr int total4 = B * D * L4;        // 16,777,216 float4 outputs
    constexpr int block  = 256;
    constexpr int grid   = total4 / block;    // 65,536 blocks

    dwconv1d_k3<<<grid, block, 0, stream>>>(in, w, bias, out);
}